// Round 1
// baseline (113.789 us; speedup 1.0000x reference)
//
#include <hip/hip_runtime.h>
#include <hip/hip_bf16.h>

// Problem constants (fixed by the reference):
constexpr int NB = 256;   // batch
constexpr int SQ = 512;   // sequence length
constexpr int ED = 512;   // encoder dim
constexpr int DD = 512;   // decoder dim
constexpr int UU = 64;    // attention units

typedef __attribute__((ext_vector_type(8))) short bf16x8;
typedef __attribute__((ext_vector_type(4))) float f32x4;

__device__ __forceinline__ unsigned short bf16_rne(float f) {
  unsigned int u = __float_as_uint(f);
  u += 0x7FFFu + ((u >> 16) & 1u);
  return (unsigned short)(u >> 16);
}

// ---------------------------------------------------------------------------
// Kernel 0: split w2 (512x64 fp32) into hi/lo bf16, pre-arranged in MFMA
// B-fragment order for mfma_f32_16x16x32_bf16:
//   B[k][col]: lane l holds k = (l>>4)*8 + j (j=0..7), col = l&15.
// ws layout (ushort): [ks 0..15][hl 0..1][nt 0..3][lane 0..63][j 0..7]
//   -> per k-step a contiguous 8192-byte block, staged to LDS linearly.
// ---------------------------------------------------------------------------
__global__ void prep_w2_frags(const float* __restrict__ w2,
                              unsigned short* __restrict__ wsb) {
  int tid = blockIdx.x * 256 + threadIdx.x;   // 0..65535
  int j    = tid & 7;
  int lane = (tid >> 3) & 63;
  int nt   = (tid >> 9) & 3;
  int hl   = (tid >> 11) & 1;
  int ks   = tid >> 12;
  int e = ks * 32 + (lane >> 4) * 8 + j;
  int u = nt * 16 + (lane & 15);
  float v = w2[e * UU + u];
  unsigned short hi = bf16_rne(v);
  unsigned short o;
  if (hl == 0) {
    o = hi;
  } else {
    float hif = __uint_as_float((unsigned int)hi << 16);
    o = bf16_rne(v - hif);   // residual, captures next ~8 mantissa bits
  }
  wsb[tid] = o;
}

// ---------------------------------------------------------------------------
// Kernel 1: fused attention. One block per batch element.
// 512 threads = 8 waves; wave w owns s-rows [w*64, w*64+64) x all 64 u.
// Proj GEMM via split-bf16 MFMA (3 mfma per tile: hi*hi + hi*lo + lo*hi).
// Then scores -> block softmax -> context accumulation (thread = e column).
// ---------------------------------------------------------------------------
__global__ __launch_bounds__(512) void attn_fused(
    const float* __restrict__ dh,    // [256,512] decoder hidden
    const float* __restrict__ x,     // [256,512,512] encoder output
    const float* __restrict__ w1,    // [512,64]
    const float* __restrict__ w1b,   // [64]
    const float* __restrict__ w2b,   // [64]
    const float* __restrict__ vk,    // [64]
    const unsigned short* __restrict__ wsb,  // w2 fragments (hi/lo)
    float* __restrict__ out)         // [256*512 ctx][256*512 att]
{
  const int b = blockIdx.x;
  const int t = threadIdx.x;
  const int wave = t >> 6;
  const int lane = t & 63;

  __shared__ float dec_lds[64];
  __shared__ float v_lds[64];
  __shared__ float red[512];
  __shared__ float score_lds[512];
  __shared__ float p_lds[512];
  __shared__ __align__(16) unsigned short bfrag[2][4096];  // dbuf x 8KB

  // ---- decoder projection: dec[u] = sum_e dh[b,e]*w1[e,u] + w1b[u] + w2b[u]
  {
    const float* dhb = dh + (size_t)b * DD;
    const int e0 = wave * 64;
    float s = 0.f;
    #pragma unroll 8
    for (int i = 0; i < 64; ++i) {
      int e = e0 + i;
      s = fmaf(dhb[e], w1[e * UU + lane], s);   // dh broadcast, w1 coalesced
    }
    red[t] = s;
  }
  __syncthreads();
  if (t < 64) {
    float d = w1b[t] + w2b[t];
    #pragma unroll
    for (int q = 0; q < 8; ++q) d += red[q * 64 + t];
    dec_lds[t] = d;
    v_lds[t] = vk[t];
    // NOTE: v_bias intentionally omitted — softmax is exactly invariant to it.
  }
  // dec_lds/v_lds consumed only after the k-loop (many barriers in between).

  // ---- projection GEMM over the whole S (single tile, no online softmax) --
  const int row0 = wave * 64;
  const float* aptr =
      x + ((size_t)b * SQ + row0 + (lane & 15)) * ED + ((lane >> 4) * 8);

  const f32x4 zero4 = {0.f, 0.f, 0.f, 0.f};
  f32x4 acc[4][4];   // [m-subtile][n-subtile]
  #pragma unroll
  for (int m = 0; m < 4; ++m)
    #pragma unroll
    for (int n = 0; n < 4; ++n) acc[m][n] = zero4;

  // stage k=0 fragments (reg-staged copy: global -> VGPR -> LDS)
  {
    bf16x8 tmp = *(const bf16x8*)(wsb + t * 8);
    *(bf16x8*)&bfrag[0][t * 8] = tmp;
  }
  // A prefetch for k=0 (fp32, 8 floats per lane per m-subtile)
  float4 acur[4][2], anxt[4][2];
  #pragma unroll
  for (int m = 0; m < 4; ++m) {
    acur[m][0] = *(const float4*)(aptr + (size_t)(m * 16) * ED);
    acur[m][1] = *(const float4*)(aptr + (size_t)(m * 16) * ED + 4);
  }

  #pragma unroll 2
  for (int k = 0; k < 16; ++k) {
    __syncthreads();               // bfrag[k&1] staged; prev reads drained
    const int buf = k & 1;
    if (k < 15) {
      // stage k+1 into the other buffer + prefetch next A
      bf16x8 tmp = *(const bf16x8*)(wsb + (k + 1) * 4096 + t * 8);
      #pragma unroll
      for (int m = 0; m < 4; ++m) {
        anxt[m][0] = *(const float4*)(aptr + (size_t)(m * 16) * ED + (k + 1) * 32);
        anxt[m][1] = *(const float4*)(aptr + (size_t)(m * 16) * ED + (k + 1) * 32 + 4);
      }
      *(bf16x8*)&bfrag[buf ^ 1][t * 8] = tmp;
    }
    // B fragments from LDS (hi at offset 0, lo at offset 2048 ushorts)
    bf16x8 bhi[4], blo[4];
    #pragma unroll
    for (int n = 0; n < 4; ++n) {
      bhi[n] = *(const bf16x8*)&bfrag[buf][n * 512 + lane * 8];
      blo[n] = *(const bf16x8*)&bfrag[buf][2048 + n * 512 + lane * 8];
    }
    // split A to hi/lo bf16 and MFMA
    #pragma unroll
    for (int m = 0; m < 4; ++m) {
      float av[8] = {acur[m][0].x, acur[m][0].y, acur[m][0].z, acur[m][0].w,
                     acur[m][1].x, acur[m][1].y, acur[m][1].z, acur[m][1].w};
      bf16x8 ahi, alo;
      #pragma unroll
      for (int i = 0; i < 8; ++i) {
        unsigned short h = bf16_rne(av[i]);
        float hf = __uint_as_float((unsigned int)h << 16);
        unsigned short l = bf16_rne(av[i] - hf);
        ahi[i] = (short)h;
        alo[i] = (short)l;
      }
      #pragma unroll
      for (int n = 0; n < 4; ++n) {
        acc[m][n] = __builtin_amdgcn_mfma_f32_16x16x32_bf16(ahi, bhi[n], acc[m][n], 0, 0, 0);
        acc[m][n] = __builtin_amdgcn_mfma_f32_16x16x32_bf16(ahi, blo[n], acc[m][n], 0, 0, 0);
        acc[m][n] = __builtin_amdgcn_mfma_f32_16x16x32_bf16(alo, bhi[n], acc[m][n], 0, 0, 0);
      }
    }
    #pragma unroll
    for (int m = 0; m < 4; ++m) {
      acur[m][0] = anxt[m][0];
      acur[m][1] = anxt[m][1];
    }
  }

  // ---- scores: score[s] = sum_u tanh(enc[s,u] + dec[u]) * v[u] -------------
  // C/D layout (verified m89/m91): col u = lane&15 (+16*nt), row = (lane>>4)*4+reg
  {
    const int ul = lane & 15;
    const int rg = lane >> 4;
    #pragma unroll
    for (int m = 0; m < 4; ++m) {
      #pragma unroll
      for (int r = 0; r < 4; ++r) {
        float part = 0.f;
        #pragma unroll
        for (int n = 0; n < 4; ++n) {
          int u = n * 16 + ul;
          float z = acc[m][n][r] + dec_lds[u];
          float ez = __expf(2.f * z);              // tanh(z) = 1 - 2/(e^2z+1)
          float th = 1.f - 2.f / (ez + 1.f);
          part = fmaf(th, v_lds[u], part);
        }
        part += __shfl_xor(part, 1);
        part += __shfl_xor(part, 2);
        part += __shfl_xor(part, 4);
        part += __shfl_xor(part, 8);               // sum over the 16 u-lanes
        if (ul == 0) score_lds[row0 + m * 16 + rg * 4 + r] = part;
      }
    }
  }
  __syncthreads();

  // ---- softmax over S (replicated per thread; deterministic & identical) --
  float mx = -1e30f;
  for (int i = 0; i < 512; i += 4) {
    float4 s4 = *(const float4*)&score_lds[i];
    mx = fmaxf(mx, fmaxf(fmaxf(s4.x, s4.y), fmaxf(s4.z, s4.w)));
  }
  p_lds[t] = __expf(score_lds[t] - mx);
  __syncthreads();
  float l = 0.f;
  for (int i = 0; i < 512; i += 4) {
    float4 p4 = *(const float4*)&p_lds[i];
    l += p4.x + p4.y + p4.z + p4.w;
  }

  // ---- context: c[e] = sum_s p[s] * x[b,s,e]; thread owns column e = t ----
  const float* xc = x + (size_t)b * SQ * ED + t;
  float c0 = 0.f, c1 = 0.f;
  #pragma unroll 4
  for (int s = 0; s < 512; s += 2) {
    c0 = fmaf(p_lds[s],     xc[(size_t)s * ED],       c0);
    c1 = fmaf(p_lds[s + 1], xc[(size_t)(s + 1) * ED], c1);
  }

  const float inv_l = 1.f / l;
  out[(size_t)b * ED + t] = (c0 + c1) * inv_l;                 // context_vector
  out[(size_t)NB * ED + (size_t)b * SQ + t] = p_lds[t] * inv_l; // att_weights
}

// ---------------------------------------------------------------------------
extern "C" void kernel_launch(void* const* d_in, const int* in_sizes, int n_in,
                              void* d_out, int out_size, void* d_ws, size_t ws_size,
                              hipStream_t stream) {
  const float* dh  = (const float*)d_in[0];  // decoder_hidden_state
  const float* x   = (const float*)d_in[1];  // encoder_output
  const float* w1  = (const float*)d_in[2];  // w1_kernel
  const float* w1b = (const float*)d_in[3];  // w1_bias
  const float* w2  = (const float*)d_in[4];  // w2_kernel
  const float* w2b = (const float*)d_in[5];  // w2_bias
  const float* vk  = (const float*)d_in[6];  // v_kernel
  // d_in[7] = v_bias: softmax is exactly invariant to it -> unused.
  unsigned short* wsb = (unsigned short*)d_ws;  // 131072 bytes used
  float* out = (float*)d_out;

  prep_w2_frags<<<256, 256, 0, stream>>>(w2, wsb);
  attn_fused<<<NB, 512, 0, stream>>>(dh, x, w1, w1b, w2b, vk, wsb, out);
}